// Round 1
// baseline (29.772 us; speedup 1.0000x reference)
//
#include <hip/hip_runtime.h>
#include <hip/hip_bf16.h>

// GuidedAttentionLoss: out = sum(w * p over valid) / count(valid)
//   w = 1 - exp(-((s/ilen - t/olen)^2) / (2*sigma^2)), valid = (t<olen)&(s<ilen)
// B=32, T=2048, S=512 (from reference); B derived from in_sizes[0].

#define GA_T 2048
#define GA_S 512
#define GA_SIGMA 0.4f
// 1/(2*sigma^2)
#define GA_INV2S2 (1.0f / (2.0f * GA_SIGMA * GA_SIGMA))

#define BLOCK 256
#define GRID1 2048

__global__ __launch_bounds__(BLOCK) void ga_partial_kernel(
    const int* __restrict__ slen, const int* __restrict__ tlen,
    const float* __restrict__ p, double* __restrict__ partial,
    int nSlots) {
  const int tid = blockIdx.x * blockDim.x + threadIdx.x;
  const int stride = gridDim.x * blockDim.x;
  const int slotsPerB = GA_T * (GA_S / 4);  // float4 slots per batch

  float acc = 0.0f;

  for (int v = tid; v < nSlots; v += stride) {
    int b = v / slotsPerB;
    int rem = v - b * slotsPerB;
    int t = rem >> 7;        // S/4 = 128 slots per row
    int sv = rem & 127;
    int ol = tlen[b];        // L2/L1-cached, 32 ints total
    if (t >= ol) continue;   // whole row invalid -> no load issued
    int il = slen[b];
    int s0 = sv << 2;
    if (s0 >= il) continue;  // slot fully beyond valid prefix

    float4 pv = *reinterpret_cast<const float4*>(p + (size_t)v * 4);

    float inv_il = 1.0f / (float)il;
    float inv_ol = 1.0f / (float)ol;
    float xo = (float)t * inv_ol;

    {
      float d = 0.0f * inv_il - xo;  // s = s0+0 always < il here
      // s0 < il guaranteed, handle 4 lanes with per-element mask
      d = (float)(s0 + 0) * inv_il - xo;
      float w = 1.0f - __expf(-(d * d) * GA_INV2S2);
      acc += w * pv.x;
    }
    if (s0 + 1 < il) {
      float d = (float)(s0 + 1) * inv_il - xo;
      float w = 1.0f - __expf(-(d * d) * GA_INV2S2);
      acc += w * pv.y;
    }
    if (s0 + 2 < il) {
      float d = (float)(s0 + 2) * inv_il - xo;
      float w = 1.0f - __expf(-(d * d) * GA_INV2S2);
      acc += w * pv.z;
    }
    if (s0 + 3 < il) {
      float d = (float)(s0 + 3) * inv_il - xo;
      float w = 1.0f - __expf(-(d * d) * GA_INV2S2);
      acc += w * pv.w;
    }
  }

  // ---- block reduction (deterministic fixed tree) ----
  // wave-level shfl reduce (wave = 64)
  for (int off = 32; off > 0; off >>= 1)
    acc += __shfl_down(acc, off, 64);

  __shared__ float wsum[BLOCK / 64];
  int lane = threadIdx.x & 63;
  int wid = threadIdx.x >> 6;
  if (lane == 0) wsum[wid] = acc;
  __syncthreads();

  if (threadIdx.x == 0) {
    float tot = 0.0f;
    for (int w = 0; w < BLOCK / 64; ++w) tot += wsum[w];
    partial[blockIdx.x] = (double)tot;
  }
}

__global__ __launch_bounds__(BLOCK) void ga_final_kernel(
    const int* __restrict__ slen, const int* __restrict__ tlen,
    const double* __restrict__ partial, int nPart, int B,
    float* __restrict__ out) {
  __shared__ double sh[BLOCK];
  double s = 0.0;
  for (int i = threadIdx.x; i < nPart; i += BLOCK) s += partial[i];
  sh[threadIdx.x] = s;
  __syncthreads();
  for (int off = BLOCK / 2; off > 0; off >>= 1) {
    if (threadIdx.x < off) sh[threadIdx.x] += sh[threadIdx.x + off];
    __syncthreads();
  }
  if (threadIdx.x == 0) {
    double den = 0.0;
    for (int b = 0; b < B; ++b)
      den += (double)slen[b] * (double)tlen[b];
    out[0] = (float)(sh[0] / den);
  }
}

extern "C" void kernel_launch(void* const* d_in, const int* in_sizes, int n_in,
                              void* d_out, int out_size, void* d_ws, size_t ws_size,
                              hipStream_t stream) {
  const int* slen = (const int*)d_in[0];
  const int* tlen = (const int*)d_in[1];
  const float* p = (const float*)d_in[2];
  float* out = (float*)d_out;
  double* partial = (double*)d_ws;  // GRID1 doubles = 16 KB

  const int B = in_sizes[0];
  const int nSlots = B * GA_T * (GA_S / 4);

  ga_partial_kernel<<<GRID1, BLOCK, 0, stream>>>(slen, tlen, p, partial, nSlots);
  ga_final_kernel<<<1, BLOCK, 0, stream>>>(slen, tlen, partial, GRID1, B, out);
}

// Round 2
// 15.888 us; speedup vs baseline: 1.8738x; 1.8738x over previous
//
#include <hip/hip_runtime.h>
#include <hip/hip_bf16.h>

// GuidedAttentionLoss: out = sum(w * p over valid) / count(valid)
//   w = 1 - exp(-((s/il - t/ol)^2) / (2*sigma^2)), valid = (t<ol)&(s<il)
// Shapes fixed by reference: B=32, T=2048, S=512.

#define GA_T 2048
#define GA_S 512
#define GA_INV2S2 (1.0f / (2.0f * 0.4f * 0.4f))

#define BLOCK 256
#define ROWS_PER_BLOCK 16            // rows of T per block
#define TILES_X (GA_T / ROWS_PER_BLOCK)  // 128
// grid = (TILES_X, B) = (128, 32) -> 4096 blocks
#define NPART (TILES_X * 32)

__global__ __launch_bounds__(BLOCK) void ga_partial_kernel(
    const int* __restrict__ slen, const int* __restrict__ tlen,
    const float* __restrict__ p, double* __restrict__ partial) {
  const int b = blockIdx.y;
  const int t0 = blockIdx.x * ROWS_PER_BLOCK;
  const int bi = b * gridDim.x + blockIdx.x;
  const int ol = tlen[b];

  float acc = 0.0f;

  if (t0 < ol) {
    const int il = slen[b];
    const float inv_il = 1.0f / (float)il;
    const float inv_ol = 1.0f / (float)ol;

    const int r = threadIdx.x >> 7;    // 0..1 (uniform per wave)
    const int sv = threadIdx.x & 127;  // column slot
    const int s0 = sv << 2;

    if (s0 < il) {
      // per-element column terms + validity masks (row-invariant)
      const float ys0 = (float)(s0 + 0) * inv_il;
      const float ys1 = (float)(s0 + 1) * inv_il;
      const float ys2 = (float)(s0 + 2) * inv_il;
      const float ys3 = (float)(s0 + 3) * inv_il;
      const float m1 = (s0 + 1 < il) ? 1.0f : 0.0f;
      const float m2 = (s0 + 2 < il) ? 1.0f : 0.0f;
      const float m3 = (s0 + 3 < il) ? 1.0f : 0.0f;

      const float* base = p + ((b * GA_T + t0 + r) * GA_S + s0);

#pragma unroll
      for (int rr = 0; rr < ROWS_PER_BLOCK; rr += 2) {
        const int t = t0 + rr + r;
        if (t >= ol) break;  // wave-uniform (r uniform per wave)
        const float4 pv = *reinterpret_cast<const float4*>(base + rr * GA_S);
        const float xo = (float)t * inv_ol;
        float d0 = ys0 - xo;
        float d1 = ys1 - xo;
        float d2 = ys2 - xo;
        float d3 = ys3 - xo;
        float w0 = 1.0f - __expf(-(d0 * d0) * GA_INV2S2);
        float w1 = 1.0f - __expf(-(d1 * d1) * GA_INV2S2);
        float w2 = 1.0f - __expf(-(d2 * d2) * GA_INV2S2);
        float w3 = 1.0f - __expf(-(d3 * d3) * GA_INV2S2);
        acc += w0 * pv.x;
        acc += m1 * w1 * pv.y;
        acc += m2 * w2 * pv.z;
        acc += m3 * w3 * pv.w;
      }
    }
  }

  // ---- block reduction (deterministic fixed tree) ----
  for (int off = 32; off > 0; off >>= 1)
    acc += __shfl_down(acc, off, 64);

  __shared__ float wsum[BLOCK / 64];
  const int lane = threadIdx.x & 63;
  const int wid = threadIdx.x >> 6;
  if (lane == 0) wsum[wid] = acc;
  __syncthreads();

  if (threadIdx.x == 0) {
    float tot = (wsum[0] + wsum[1]) + (wsum[2] + wsum[3]);
    partial[bi] = (double)tot;  // always written (ws not re-poisoned, but we
                                // fully overwrite every call)
  }
}

__global__ __launch_bounds__(BLOCK) void ga_final_kernel(
    const int* __restrict__ slen, const int* __restrict__ tlen,
    const double* __restrict__ partial, int B, float* __restrict__ out) {
  // NPART = 4096, 256 threads -> 16 loads/thread, 4 independent accumulators
  double a0 = 0.0, a1 = 0.0, a2 = 0.0, a3 = 0.0;
#pragma unroll
  for (int k = 0; k < NPART / BLOCK; k += 4) {
    a0 += partial[(k + 0) * BLOCK + threadIdx.x];
    a1 += partial[(k + 1) * BLOCK + threadIdx.x];
    a2 += partial[(k + 2) * BLOCK + threadIdx.x];
    a3 += partial[(k + 3) * BLOCK + threadIdx.x];
  }
  double s = (a0 + a1) + (a2 + a3);

  __shared__ double sh[BLOCK];
  sh[threadIdx.x] = s;
  __syncthreads();
  for (int off = BLOCK / 2; off > 0; off >>= 1) {
    if (threadIdx.x < off) sh[threadIdx.x] += sh[threadIdx.x + off];
    __syncthreads();
  }
  if (threadIdx.x == 0) {
    double den = 0.0;
#pragma unroll
    for (int b = 0; b < 32; ++b)
      den += (double)slen[b] * (double)tlen[b];
    out[0] = (float)(sh[0] / den);
  }
}

extern "C" void kernel_launch(void* const* d_in, const int* in_sizes, int n_in,
                              void* d_out, int out_size, void* d_ws, size_t ws_size,
                              hipStream_t stream) {
  const int* slen = (const int*)d_in[0];
  const int* tlen = (const int*)d_in[1];
  const float* p = (const float*)d_in[2];
  float* out = (float*)d_out;
  double* partial = (double*)d_ws;  // NPART doubles = 32 KB

  const int B = in_sizes[0];  // 32
  dim3 grid(TILES_X, B);
  ga_partial_kernel<<<grid, BLOCK, 0, stream>>>(slen, tlen, p, partial);
  ga_final_kernel<<<1, BLOCK, 0, stream>>>(slen, tlen, partial, B, out);
}